// Round 1
// 539.617 us; speedup vs baseline: 1.1207x; 1.1207x over previous
//
#include <hip/hip_runtime.h>
#include <hip/hip_fp16.h>

#define IN_F 4096
#define OUT_F 4096
#define TOK 8192
#define NNZ_PER_ROW 205
#define NNZ (OUT_F * NNZ_PER_ROW)

typedef __attribute__((ext_vector_type(8))) _Float16 f16x8;
typedef __attribute__((ext_vector_type(4))) float floatx4;

// ---------------- prep kernels (unchanged, known-good) ----------------

__global__ __launch_bounds__(256) void cvt_x_kernel(const float* __restrict__ x,
                                                    _Float16* __restrict__ xh) {
    int t = blockIdx.x * 256 + threadIdx.x;      // one thread = 8 elements
    const float4* p = (const float4*)x + (size_t)t * 2;
    float4 a = p[0], b = p[1];
    f16x8 h;
    h[0] = (_Float16)a.x; h[1] = (_Float16)a.y; h[2] = (_Float16)a.z; h[3] = (_Float16)a.w;
    h[4] = (_Float16)b.x; h[5] = (_Float16)b.y; h[6] = (_Float16)b.z; h[7] = (_Float16)b.w;
    ((f16x8*)xh)[t] = h;
}

__global__ __launch_bounds__(256) void dequant_w_kernel(const int* __restrict__ bp,
                                                        const float* __restrict__ scales,
                                                        _Float16* __restrict__ wh) {
    int t = blockIdx.x * 256 + threadIdx.x;      // one thread = 8 elements
    int row = t >> 9;                            // 512 threads per 4096-wide row
    float s = scales[row];
    const int4* p = (const int4*)bp + (size_t)t * 2;
    int4 a = p[0], b = p[1];
    f16x8 h;
    h[0] = (_Float16)((float)(a.x - 128) * s);
    h[1] = (_Float16)((float)(a.y - 128) * s);
    h[2] = (_Float16)((float)(a.z - 128) * s);
    h[3] = (_Float16)((float)(a.w - 128) * s);
    h[4] = (_Float16)((float)(b.x - 128) * s);
    h[5] = (_Float16)((float)(b.y - 128) * s);
    h[6] = (_Float16)((float)(b.z - 128) * s);
    h[7] = (_Float16)((float)(b.w - 128) * s);
    ((f16x8*)wh)[t] = h;
}

__global__ __launch_bounds__(256) void sparse_add_kernel(const void* __restrict__ vals_raw,
                                                         const int* __restrict__ cols,
                                                         _Float16* __restrict__ wh) {
    int k = blockIdx.x * 256 + threadIdx.x;
    if (k >= NNZ) return;

    const float*    vf = (const float*)vals_raw;
    const _Float16* vh = (const _Float16*)vals_raw;
    float mx = 0.f;
    for (int i = 0; i < 64; ++i) {
        float a = __builtin_fabsf(vf[i]);
        mx = a > mx ? a : mx;
    }
    const bool is_f32 = (mx > 1e-6f) && (mx < 1.0f);

    int row  = k / NNZ_PER_ROW;
    int rbeg = row * NNZ_PER_ROW;
    int rend = rbeg + NNZ_PER_ROW;
    int c    = cols[k];
    if (k != rbeg && cols[k - 1] == c) return;   // not first of its run

    float s = is_f32 ? vf[k] : (float)vh[k];
    for (int k2 = k + 1; k2 < rend && cols[k2] == c; ++k2)
        s += is_f32 ? vf[k2] : (float)vh[k2];

    _Float16* p = wh + (size_t)row * IN_F + c;
    *p = (_Float16)((float)*p + s);
}

// ---------------- GEMM: 256x256 tile, 8-phase counted-vmcnt schedule --------
// out[T][O] = Xh[T][K] * Wh[O][K]^T.  BM=BN=256, BK=64, 512 thr = 8 waves
// (2M x 4N), per-wave C = 128x64 -> acc[8][4] x floatx4.
//
// LDS (dynamic, 128 KiB), per 64KB buffer b (base = b*65536):
//   A_kk0 @ +0      A_kk1 @ +16384   B_kk0 @ +32768   B_kk1 @ +49152
// Each half-tile: 256 rows x 32 halfs (64B rows).  Swizzle: 16B slot s of
// row r holds global K-chunk s ^ f(r), f(r) = (r&3)^((r>>2)&3).  Staging
// keeps the LDS dest linear (global_load_lds requirement) and permutes the
// GLOBAL source per lane; reads apply the same XOR (involution).
//
// Phase schedule per K-tile kt (buffer kt&1):
//   ph0: read B_kk0(all nt) + A_kk0(mq0); stage A_kk1(kt+1); barrier; 16 MFMA; barrier
//   ph1: read A_kk0(mq1);                 stage B_kk0(kt+2); barrier; 16 MFMA; barrier
//   ph2: read B_kk1(all nt) + A_kk1(mq0); stage A_kk0(kt+2); barrier; 16 MFMA; barrier
//   ph3: read A_kk1(mq1);                 stage B_kk1(kt+2); barrier; 16 MFMA;
//        vmcnt(6) [vmcnt(0) before last K-tile]; barrier
// Race-freedom: each half's LAST ds_read phase (B0:0, A0:1, B1:2, A1:3) is
// exactly one phase before the stage that overwrites it (stages issue after
// the previous phase's trailing barrier, which all waves pass only after
// their ds_reads completed).  vmcnt(6) = 2 loads x 3 half-tiles in flight,
// so K-tile kt+1 is fully landed before any wave reads it.

__global__ __launch_bounds__(512, 2) void gemm256_kernel(const _Float16* __restrict__ X,
                                                         const _Float16* __restrict__ W,
                                                         float* __restrict__ out) {
    extern __shared__ char smem[];               // 131072 bytes
    const int tid  = threadIdx.x;
    const int lane = tid & 63;
    const int w    = tid >> 6;                   // 0..7
    const int wm   = w >> 2;                     // 0..1  (M)
    const int wn   = w & 3;                      // 0..3  (N)

    // bijective XCD swizzle: 512 blocks, 64 contiguous logical tiles per XCD
    const int bid = blockIdx.x;
    const int swz = (bid & 7) * 64 + (bid >> 3);
    const int bm  = swz >> 4;                    // 0..31
    const int bn  = swz & 15;                    // 0..15

    const _Float16* Ap = X + (size_t)(bm * 256) * IN_F;
    const _Float16* Bp = W + (size_t)(bn * 256) * IN_F;

    // staging lane geometry: chunk ch = w*2+j (16 rows x 64B = 1024B each)
    int srow[2], sg[2];
#pragma unroll
    for (int j = 0; j < 2; ++j) {
        int ch  = w * 2 + j;
        int r   = ch * 16 + (lane >> 2);
        srow[j] = r;
        sg[j]   = (lane & 3) ^ ((r & 3) ^ ((r >> 2) & 3));
    }

    auto stage = [&](const _Float16* panel, int ldsOff, int kcol) {
#pragma unroll
        for (int j = 0; j < 2; ++j) {
            const _Float16* gp = panel + (size_t)srow[j] * IN_F + kcol + sg[j] * 8;
            char* lp = smem + ldsOff + (w * 2 + j) * 1024;   // wave-uniform base
            __builtin_amdgcn_global_load_lds(
                (const __attribute__((address_space(1))) void*)gp,
                (__attribute__((address_space(3))) void*)lp, 16, 0, 0);
        }
    };

    const int q    = lane >> 4;
    const int r15  = lane & 15;
    const int slot = (q ^ ((r15 & 3) ^ ((r15 >> 2) & 3))) * 16;  // per-lane const

    floatx4 acc[8][4] = {};
    f16x8 afrag[4], bfrag[4];

#define LOAD_B(KKH) do {                                                        \
    const char* Bb = smem + buf + 32768 + (KKH) * 16384;                        \
    _Pragma("unroll")                                                           \
    for (int nt = 0; nt < 4; ++nt)                                              \
        bfrag[nt] = *(const f16x8*)(Bb + (wn * 64 + nt * 16 + r15) * 64 + slot);\
} while (0)

#define LOAD_A(MQ, KKH) do {                                                    \
    const char* Ab = smem + buf + (KKH) * 16384;                                \
    _Pragma("unroll")                                                           \
    for (int mt = 0; mt < 4; ++mt)                                              \
        afrag[mt] = *(const f16x8*)(Ab + (wm * 128 + (MQ) * 64 + mt * 16 + r15) * 64 + slot);\
} while (0)

#define MFMA_BLK(MQ) do {                                                       \
    __builtin_amdgcn_s_setprio(1);                                              \
    _Pragma("unroll")                                                           \
    for (int mt = 0; mt < 4; ++mt)                                              \
        _Pragma("unroll")                                                       \
        for (int nt = 0; nt < 4; ++nt)                                          \
            acc[(MQ) * 4 + mt][nt] = __builtin_amdgcn_mfma_f32_16x16x32_f16(    \
                afrag[mt], bfrag[nt], acc[(MQ) * 4 + mt][nt], 0, 0, 0);         \
    __builtin_amdgcn_s_setprio(0);                                              \
} while (0)

    // prologue: B0(0),A0(0),B1(0),A1(0),B0(1),A0(1),B1(1)  (7 halves, 14 loads)
    stage(Bp, 32768, 0);
    stage(Ap, 0, 0);
    stage(Bp, 49152, 32);
    stage(Ap, 16384, 32);
    stage(Bp, 65536 + 32768, 64);
    stage(Ap, 65536 + 0, 64);
    stage(Bp, 65536 + 49152, 96);
    asm volatile("s_waitcnt vmcnt(6)" ::: "memory");   // K-tile 0 fully landed
    __builtin_amdgcn_s_barrier();

    for (int kt = 0; kt < 64; ++kt) {
        const int buf = (kt & 1) << 16;
        const int ks1 = kt + 1, ks2 = kt + 2;
        const int b1  = (ks1 & 1) << 16;
        const int b2  = (ks2 & 1) << 16;

        // ---- phase 0: kk0 / mq0 ; stage A_kk1(kt+1)
        LOAD_B(0);
        LOAD_A(0, 0);
        if (ks1 < 64) stage(Ap, b1 + 16384, ks1 * 64 + 32);
        __builtin_amdgcn_s_barrier();
        MFMA_BLK(0);
        __builtin_amdgcn_s_barrier();

        // ---- phase 1: kk0 / mq1 ; stage B_kk0(kt+2)
        LOAD_A(1, 0);
        if (ks2 < 64) stage(Bp, b2 + 32768, ks2 * 64);
        __builtin_amdgcn_s_barrier();
        MFMA_BLK(1);
        __builtin_amdgcn_s_barrier();

        // ---- phase 2: kk1 / mq0 ; stage A_kk0(kt+2)
        LOAD_B(1);
        LOAD_A(0, 1);
        if (ks2 < 64) stage(Ap, b2, ks2 * 64);
        __builtin_amdgcn_s_barrier();
        MFMA_BLK(0);
        __builtin_amdgcn_s_barrier();

        // ---- phase 3: kk1 / mq1 ; stage B_kk1(kt+2); counted vmcnt
        LOAD_A(1, 1);
        if (ks2 < 64) stage(Bp, b2 + 49152, ks2 * 64 + 32);
        __builtin_amdgcn_s_barrier();
        MFMA_BLK(1);
        if (kt < 62)       asm volatile("s_waitcnt vmcnt(6)" ::: "memory");
        else if (kt == 62) asm volatile("s_waitcnt vmcnt(0)" ::: "memory");
        __builtin_amdgcn_s_barrier();
    }

#undef LOAD_B
#undef LOAD_A
#undef MFMA_BLK

#pragma unroll
    for (int mq = 0; mq < 2; ++mq)
#pragma unroll
        for (int mt = 0; mt < 4; ++mt)
#pragma unroll
            for (int nt = 0; nt < 4; ++nt) {
                const int o    = bn * 256 + wn * 64 + nt * 16 + r15;
                const int trow = bm * 256 + wm * 128 + mq * 64 + mt * 16 + q * 4;
                const floatx4 v = acc[mq * 4 + mt][nt];
#pragma unroll
                for (int r = 0; r < 4; ++r)
                    out[(size_t)(trow + r) * OUT_F + o] = v[r];
            }
}

// ---------------- GEMM fallbacks (previous known-good kernels) -------------

__global__ __launch_bounds__(256) void gemm_fast_kernel(const _Float16* __restrict__ X,
                                                        const _Float16* __restrict__ W,
                                                        float* __restrict__ out) {
    __shared__ __align__(1024) char smem[32768];   // A: [0,16K)  B: [16K,32K)
    const int tid  = threadIdx.x;
    const int lane = tid & 63;
    const int w    = tid >> 6;
    const int wm   = w >> 1;
    const int wn   = w & 1;
    const int bm   = blockIdx.y;
    const int bn   = blockIdx.x;

    const int l8 = lane >> 3;
    const int ls = lane & 7;
    const int e  = ls ^ l8;

    floatx4 acc[4][4] = {};

    for (int k0 = 0; k0 < IN_F; k0 += 64) {
#pragma unroll
        for (int j = 0; j < 4; ++j) {
            int c   = w * 4 + j;
            int row = c * 8 + l8;
            const _Float16* gp = X + ((size_t)(bm * 128 + row)) * IN_F + k0 + e * 8;
            char* lp = smem + c * 1024;
            __builtin_amdgcn_global_load_lds((const __attribute__((address_space(1))) void*)gp,
                                             (__attribute__((address_space(3))) void*)lp,
                                             16, 0, 0);
        }
#pragma unroll
        for (int j = 0; j < 4; ++j) {
            int c   = w * 4 + j;
            int row = c * 8 + l8;
            const _Float16* gp = W + ((size_t)(bn * 128 + row)) * IN_F + k0 + e * 8;
            char* lp = smem + 16384 + c * 1024;
            __builtin_amdgcn_global_load_lds((const __attribute__((address_space(1))) void*)gp,
                                             (__attribute__((address_space(3))) void*)lp,
                                             16, 0, 0);
        }
        __syncthreads();

        const int q   = lane >> 4;
        const int r15 = lane & 15;
#pragma unroll
        for (int kk = 0; kk < 64; kk += 32) {
            int j = (kk >> 3) + q;
            f16x8 a[4], b[4];
#pragma unroll
            for (int mt = 0; mt < 4; ++mt) {
                int row = wm * 64 + mt * 16 + r15;
                a[mt] = *(const f16x8*)(smem + row * 128 + ((j ^ (row & 7)) * 16));
            }
#pragma unroll
            for (int nt = 0; nt < 4; ++nt) {
                int row = wn * 64 + nt * 16 + r15;
                b[nt] = *(const f16x8*)(smem + 16384 + row * 128 + ((j ^ (row & 7)) * 16));
            }
#pragma unroll
            for (int mt = 0; mt < 4; ++mt)
#pragma unroll
                for (int nt = 0; nt < 4; ++nt)
                    acc[mt][nt] = __builtin_amdgcn_mfma_f32_16x16x32_f16(a[mt], b[nt],
                                                                         acc[mt][nt], 0, 0, 0);
        }
        __syncthreads();
    }

    const int q   = lane >> 4;
    const int r15 = lane & 15;
#pragma unroll
    for (int mt = 0; mt < 4; ++mt)
#pragma unroll
        for (int nt = 0; nt < 4; ++nt) {
            int o     = bn * 128 + wn * 64 + nt * 16 + r15;
            int tbase = bm * 128 + wm * 64 + mt * 16 + q * 4;
#pragma unroll
            for (int r = 0; r < 4; ++r)
                out[(size_t)(tbase + r) * OUT_F + o] = acc[mt][nt][r];
        }
}

__global__ __launch_bounds__(256) void gemm_kernel(const float* __restrict__ X,
                                                   const _Float16* __restrict__ W,
                                                   float* __restrict__ out) {
    __shared__ __align__(16) _Float16 As[128 * 72];
    __shared__ __align__(16) _Float16 Bs[128 * 72];
    const int tid  = threadIdx.x;
    const int lane = tid & 63;
    const int w    = tid >> 6;
    const int wm   = w >> 1;
    const int wn   = w & 1;
    const int bm   = blockIdx.y;
    const int bn   = blockIdx.x;
    const int srow = tid >> 3;
    const int sch  = tid & 7;

    const float*    Xb = X + (size_t)(bm * 128) * IN_F;
    const _Float16* Wb = W + (size_t)(bn * 128) * IN_F;

    floatx4 acc[4][4] = {};

    for (int k0 = 0; k0 < IN_F; k0 += 64) {
#pragma unroll
        for (int p = 0; p < 4; ++p) {
            int row = p * 32 + srow;
            const float* gp = Xb + (size_t)row * IN_F + k0 + sch * 8;
            float4 u = ((const float4*)gp)[0];
            float4 v = ((const float4*)gp)[1];
            f16x8 h;
            h[0] = (_Float16)u.x; h[1] = (_Float16)u.y;
            h[2] = (_Float16)u.z; h[3] = (_Float16)u.w;
            h[4] = (_Float16)v.x; h[5] = (_Float16)v.y;
            h[6] = (_Float16)v.z; h[7] = (_Float16)v.w;
            *(f16x8*)&As[row * 72 + sch * 8] = h;
        }
#pragma unroll
        for (int p = 0; p < 4; ++p) {
            int row = p * 32 + srow;
            *(f16x8*)&Bs[row * 72 + sch * 8] =
                *(const f16x8*)(Wb + (size_t)row * IN_F + k0 + sch * 8);
        }
        __syncthreads();

        const int q   = lane >> 4;
        const int r15 = lane & 15;
#pragma unroll
        for (int kk = 0; kk < 64; kk += 32) {
            int j = (kk >> 3) + q;
            f16x8 a[4], b[4];
#pragma unroll
            for (int mt = 0; mt < 4; ++mt) {
                int row = wm * 64 + mt * 16 + r15;
                a[mt] = *(const f16x8*)&As[row * 72 + j * 8];
            }
#pragma unroll
            for (int nt = 0; nt < 4; ++nt) {
                int row = wn * 64 + nt * 16 + r15;
                b[nt] = *(const f16x8*)&Bs[row * 72 + j * 8];
            }
#pragma unroll
            for (int mt = 0; mt < 4; ++mt)
#pragma unroll
                for (int nt = 0; nt < 4; ++nt)
                    acc[mt][nt] = __builtin_amdgcn_mfma_f32_16x16x32_f16(a[mt], b[nt],
                                                                         acc[mt][nt], 0, 0, 0);
        }
        __syncthreads();
    }

    const int q   = lane >> 4;
    const int r15 = lane & 15;
#pragma unroll
    for (int mt = 0; mt < 4; ++mt)
#pragma unroll
        for (int nt = 0; nt < 4; ++nt) {
            int o     = bn * 128 + wn * 64 + nt * 16 + r15;
            int tbase = bm * 128 + wm * 64 + mt * 16 + q * 4;
#pragma unroll
            for (int r = 0; r < 4; ++r)
                out[(size_t)(tbase + r) * OUT_F + o] = acc[mt][nt][r];
        }
}

// ---------------- launch ----------------

extern "C" void kernel_launch(void* const* d_in, const int* in_sizes, int n_in,
                              void* d_out, int out_size, void* d_ws, size_t ws_size,
                              hipStream_t stream) {
    const float* x      = (const float*)d_in[0];
    const int*   bp     = (const int*)d_in[1];
    const float* scales = (const float*)d_in[2];
    const void*  vals   = (const void*)d_in[3];
    const int*   cols   = (const int*)d_in[4];
    float*       out    = (float*)d_out;

    _Float16* wh = (_Float16*)d_ws;                                    // 33.5 MB
    const size_t wh_bytes = (size_t)OUT_F * IN_F * 2;
    const size_t xh_bytes = (size_t)TOK * IN_F * 2;                    // 67 MB

    static int use256 = -1;
    if (use256 < 0) {
        hipError_t e = hipFuncSetAttribute((const void*)gemm256_kernel,
                                           hipFuncAttributeMaxDynamicSharedMemorySize,
                                           131072);
        use256 = (e == hipSuccess) ? 1 : 0;
    }

    dequant_w_kernel<<<OUT_F * IN_F / 8 / 256, 256, 0, stream>>>(bp, scales, wh);
    sparse_add_kernel<<<(NNZ + 255) / 256, 256, 0, stream>>>(vals, cols, wh);

    if (ws_size >= wh_bytes + xh_bytes) {
        _Float16* xh = (_Float16*)((char*)d_ws + wh_bytes);
        cvt_x_kernel<<<TOK * IN_F / 8 / 256, 256, 0, stream>>>(x, xh);
        if (use256) {
            gemm256_kernel<<<dim3(512), 512, 131072, stream>>>(xh, wh, out);
        } else {
            dim3 grid(OUT_F / 128, TOK / 128);
            gemm_fast_kernel<<<grid, 256, 0, stream>>>(xh, wh, out);
        }
    } else {
        dim3 grid(OUT_F / 128, TOK / 128);
        gemm_kernel<<<grid, 256, 0, stream>>>(x, wh, out);
    }
}

// Round 2
// 523.978 us; speedup vs baseline: 1.1542x; 1.0298x over previous
//
#include <hip/hip_runtime.h>
#include <hip/hip_fp16.h>

#define IN_F 4096
#define OUT_F 4096
#define TOK 8192
#define NNZ_PER_ROW 205
#define NNZ (OUT_F * NNZ_PER_ROW)

typedef __attribute__((ext_vector_type(8))) _Float16 f16x8;
typedef __attribute__((ext_vector_type(4))) float floatx4;

// ---------------- prep kernels (unchanged, known-good) ----------------

__global__ __launch_bounds__(256) void cvt_x_kernel(const float* __restrict__ x,
                                                    _Float16* __restrict__ xh) {
    int t = blockIdx.x * 256 + threadIdx.x;      // one thread = 8 elements
    const float4* p = (const float4*)x + (size_t)t * 2;
    float4 a = p[0], b = p[1];
    f16x8 h;
    h[0] = (_Float16)a.x; h[1] = (_Float16)a.y; h[2] = (_Float16)a.z; h[3] = (_Float16)a.w;
    h[4] = (_Float16)b.x; h[5] = (_Float16)b.y; h[6] = (_Float16)b.z; h[7] = (_Float16)b.w;
    ((f16x8*)xh)[t] = h;
}

__global__ __launch_bounds__(256) void dequant_w_kernel(const int* __restrict__ bp,
                                                        const float* __restrict__ scales,
                                                        _Float16* __restrict__ wh) {
    int t = blockIdx.x * 256 + threadIdx.x;      // one thread = 8 elements
    int row = t >> 9;                            // 512 threads per 4096-wide row
    float s = scales[row];
    const int4* p = (const int4*)bp + (size_t)t * 2;
    int4 a = p[0], b = p[1];
    f16x8 h;
    h[0] = (_Float16)((float)(a.x - 128) * s);
    h[1] = (_Float16)((float)(a.y - 128) * s);
    h[2] = (_Float16)((float)(a.z - 128) * s);
    h[3] = (_Float16)((float)(a.w - 128) * s);
    h[4] = (_Float16)((float)(b.x - 128) * s);
    h[5] = (_Float16)((float)(b.y - 128) * s);
    h[6] = (_Float16)((float)(b.z - 128) * s);
    h[7] = (_Float16)((float)(b.w - 128) * s);
    ((f16x8*)wh)[t] = h;
}

__global__ __launch_bounds__(256) void sparse_add_kernel(const void* __restrict__ vals_raw,
                                                         const int* __restrict__ cols,
                                                         _Float16* __restrict__ wh) {
    int k = blockIdx.x * 256 + threadIdx.x;
    if (k >= NNZ) return;

    const float*    vf = (const float*)vals_raw;
    const _Float16* vh = (const _Float16*)vals_raw;
    float mx = 0.f;
    for (int i = 0; i < 64; ++i) {
        float a = __builtin_fabsf(vf[i]);
        mx = a > mx ? a : mx;
    }
    const bool is_f32 = (mx > 1e-6f) && (mx < 1.0f);

    int row  = k / NNZ_PER_ROW;
    int rbeg = row * NNZ_PER_ROW;
    int rend = rbeg + NNZ_PER_ROW;
    int c    = cols[k];
    if (k != rbeg && cols[k - 1] == c) return;   // not first of its run

    float s = is_f32 ? vf[k] : (float)vh[k];
    for (int k2 = k + 1; k2 < rend && cols[k2] == c; ++k2)
        s += is_f32 ? vf[k2] : (float)vh[k2];

    _Float16* p = wh + (size_t)row * IN_F + c;
    *p = (_Float16)((float)*p + s);
}

// ---------------- GEMM: 256x256 tile, 8-phase counted-vmcnt schedule --------
// out[T][O] = Xh[T][K] * Wh[O][K]^T.  BM=BN=256, BK=64, 512 thr = 8 waves
// (2M x 4N), per-wave C = 128x64 -> acc[8][4] x floatx4.
//
// LDS (dynamic, 128 KiB), per 64KB buffer b (base = b*65536):
//   A @ +0 (256 rows x 128B)    B @ +32768 (256 rows x 128B)
// Row layout = round-0's MEASURED-ZERO-CONFLICT pattern: 128B rows, 8 slots
// of 16B; slot s of row r holds global 16B K-chunk s ^ (r&7).  Staging keeps
// the LDS dest linear (global_load_lds requirement) and permutes the GLOBAL
// source per lane (e = (lane&7) ^ (lane>>3), per-lane constant); MFMA reads
// use slot = ((KKH*4+q) ^ (r&7))*16.
//
// Stage units (16KB = 16 chunks of 1024B, 2 chunks/wave):
//   A1 = A rows 0-127, A2 = rows 128-255, B1/B2 same for B.
// Per-tile slots: ph0 stage A1(kt+1), ph1 stage A2(kt+1), ph2 none,
// ph3 stage B1(kt+2)+B2(kt+2); one s_waitcnt vmcnt(4) at ph3 end (the two
// B stages just issued remain in flight).  Race-freedom: every region's
// last ds_read is consumed by that phase's MFMA before its trailing
// barrier, and the overwriting stage issues >=1 barrier later:
//   A of buf: last read ph3 -> A(kt+1) staged (other buf) ph0/ph1  OK
//   B of buf: last read ph2 -> B(kt+2) staged (same buf)  ph3      OK
// Landing: tile kt units issued at (kt-1){ph0,ph1} and (kt-2)ph3; the
// vmcnt(4) at (kt-1)ph3 leaves only that phase's 4 loads outstanding.

__global__ __launch_bounds__(512, 2) void gemm256_kernel(const _Float16* __restrict__ X,
                                                         const _Float16* __restrict__ W,
                                                         float* __restrict__ out) {
    extern __shared__ char smem[];               // 131072 bytes
    const int tid  = threadIdx.x;
    const int lane = tid & 63;
    const int w    = tid >> 6;                   // 0..7
    const int wm   = w >> 2;                     // 0..1  (M)
    const int wn   = w & 3;                      // 0..3  (N)

    // bijective XCD swizzle: 512 blocks, 64 contiguous logical tiles per XCD
    const int bid = blockIdx.x;
    const int swz = (bid & 7) * 64 + (bid >> 3);
    const int bm  = swz >> 4;                    // 0..31
    const int bn  = swz & 15;                    // 0..15

    const _Float16* Ap = X + (size_t)(bm * 256) * IN_F;
    const _Float16* Bp = W + (size_t)(bn * 256) * IN_F;

    // staging lane geometry: chunk = 8 rows x 128B = 1024B; within a chunk
    // lane>>3 = row, lane&7 = LDS slot; global chunk fetched = slot ^ row&7.
    const int l8 = lane >> 3;
    const int e  = (lane & 7) ^ l8;              // per-lane constant

    auto stage = [&](const _Float16* panel, int ldsBase, int rowBase, int kcol) {
#pragma unroll
        for (int j = 0; j < 2; ++j) {
            int ch = w * 2 + j;
            const _Float16* gp = panel + (size_t)(rowBase + ch * 8 + l8) * IN_F + kcol + e * 8;
            char* lp = smem + ldsBase + ch * 1024;   // wave-uniform base
            __builtin_amdgcn_global_load_lds(
                (const __attribute__((address_space(1))) void*)gp,
                (__attribute__((address_space(3))) void*)lp, 16, 0, 0);
        }
    };

    const int q     = lane >> 4;
    const int r15   = lane & 15;
    const int slot0 = (q ^ (r15 & 7)) * 16;      // kk0 slot byte; kk1 = slot0^64

    floatx4 acc[8][4] = {};
    f16x8 afrag[4], bfrag[4];

#define LOAD_B(KKH) do {                                                        \
    const char* Bb = smem + buf + 32768;                                        \
    _Pragma("unroll")                                                           \
    for (int nt = 0; nt < 4; ++nt)                                              \
        bfrag[nt] = *(const f16x8*)(Bb + (wn * 64 + nt * 16 + r15) * 128        \
                                       + (slot0 ^ ((KKH) * 64)));               \
} while (0)

#define LOAD_A(MQ, KKH) do {                                                    \
    const char* Ab = smem + buf;                                                \
    _Pragma("unroll")                                                           \
    for (int mt = 0; mt < 4; ++mt)                                              \
        afrag[mt] = *(const f16x8*)(Ab + (wm * 128 + (MQ) * 64 + mt * 16 + r15) * 128 \
                                       + (slot0 ^ ((KKH) * 64)));               \
} while (0)

#define MFMA_BLK(MQ) do {                                                       \
    __builtin_amdgcn_s_setprio(1);                                              \
    _Pragma("unroll")                                                           \
    for (int mt = 0; mt < 4; ++mt)                                              \
        _Pragma("unroll")                                                       \
        for (int nt = 0; nt < 4; ++nt)                                          \
            acc[(MQ) * 4 + mt][nt] = __builtin_amdgcn_mfma_f32_16x16x32_f16(    \
                afrag[mt], bfrag[nt], acc[(MQ) * 4 + mt][nt], 0, 0, 0);         \
    __builtin_amdgcn_s_setprio(0);                                              \
} while (0)

    // prologue: tile 0 fully + B1(1),B2(1); vmcnt(4) leaves the latter in flight
    stage(Bp, 32768, 0, 0);            // B1(0)
    stage(Bp, 49152, 128, 0);          // B2(0)
    stage(Ap, 0, 0, 0);                // A1(0)
    stage(Ap, 16384, 128, 0);          // A2(0)
    stage(Bp, 65536 + 32768, 0, 64);   // B1(1)
    stage(Bp, 65536 + 49152, 128, 64); // B2(1)
    asm volatile("s_waitcnt vmcnt(4)" ::: "memory");   // tile 0 fully landed
    __builtin_amdgcn_s_barrier();

    for (int kt = 0; kt < 64; ++kt) {
        const int buf = (kt & 1) << 16;
        const int ob  = ((kt + 1) & 1) << 16;    // other buffer

        // ---- phase 0: kk0 / mq0 ; stage A1(kt+1)
        LOAD_B(0);
        LOAD_A(0, 0);
        if (kt < 63) stage(Ap, ob, 0, (kt + 1) * 64);
        __builtin_amdgcn_s_barrier();
        MFMA_BLK(0);
        __builtin_amdgcn_s_barrier();

        // ---- phase 1: kk0 / mq1 ; stage A2(kt+1)
        LOAD_A(1, 0);
        if (kt < 63) stage(Ap, ob + 16384, 128, (kt + 1) * 64);
        __builtin_amdgcn_s_barrier();
        MFMA_BLK(1);
        __builtin_amdgcn_s_barrier();

        // ---- phase 2: kk1 / mq0 ; (no stage: B of buf still being read)
        LOAD_B(1);
        LOAD_A(0, 1);
        __builtin_amdgcn_s_barrier();
        MFMA_BLK(0);
        __builtin_amdgcn_s_barrier();

        // ---- phase 3: kk1 / mq1 ; stage B1(kt+2)+B2(kt+2); counted vmcnt
        LOAD_A(1, 1);
        if (kt < 62) {
            stage(Bp, buf + 32768, 0, (kt + 2) * 64);
            stage(Bp, buf + 49152, 128, (kt + 2) * 64);
        }
        __builtin_amdgcn_s_barrier();
        MFMA_BLK(1);
        if (kt < 62)       asm volatile("s_waitcnt vmcnt(4)" ::: "memory");
        else if (kt == 62) asm volatile("s_waitcnt vmcnt(0)" ::: "memory");
        __builtin_amdgcn_s_barrier();
    }

#undef LOAD_B
#undef LOAD_A
#undef MFMA_BLK

#pragma unroll
    for (int mq = 0; mq < 2; ++mq)
#pragma unroll
        for (int mt = 0; mt < 4; ++mt)
#pragma unroll
            for (int nt = 0; nt < 4; ++nt) {
                const int o    = bn * 256 + wn * 64 + nt * 16 + r15;
                const int trow = bm * 256 + wm * 128 + mq * 64 + mt * 16 + q * 4;
                const floatx4 v = acc[mq * 4 + mt][nt];
#pragma unroll
                for (int r = 0; r < 4; ++r)
                    out[(size_t)(trow + r) * OUT_F + o] = v[r];
            }
}

// ---------------- GEMM fallbacks (previous known-good kernels) -------------

__global__ __launch_bounds__(256) void gemm_fast_kernel(const _Float16* __restrict__ X,
                                                        const _Float16* __restrict__ W,
                                                        float* __restrict__ out) {
    __shared__ __align__(1024) char smem[32768];   // A: [0,16K)  B: [16K,32K)
    const int tid  = threadIdx.x;
    const int lane = tid & 63;
    const int w    = tid >> 6;
    const int wm   = w >> 1;
    const int wn   = w & 1;
    const int bm   = blockIdx.y;
    const int bn   = blockIdx.x;

    const int l8 = lane >> 3;
    const int ls = lane & 7;
    const int e  = ls ^ l8;

    floatx4 acc[4][4] = {};

    for (int k0 = 0; k0 < IN_F; k0 += 64) {
#pragma unroll
        for (int j = 0; j < 4; ++j) {
            int c   = w * 4 + j;
            int row = c * 8 + l8;
            const _Float16* gp = X + ((size_t)(bm * 128 + row)) * IN_F + k0 + e * 8;
            char* lp = smem + c * 1024;
            __builtin_amdgcn_global_load_lds((const __attribute__((address_space(1))) void*)gp,
                                             (__attribute__((address_space(3))) void*)lp,
                                             16, 0, 0);
        }
#pragma unroll
        for (int j = 0; j < 4; ++j) {
            int c   = w * 4 + j;
            int row = c * 8 + l8;
            const _Float16* gp = W + ((size_t)(bn * 128 + row)) * IN_F + k0 + e * 8;
            char* lp = smem + 16384 + c * 1024;
            __builtin_amdgcn_global_load_lds((const __attribute__((address_space(1))) void*)gp,
                                             (__attribute__((address_space(3))) void*)lp,
                                             16, 0, 0);
        }
        __syncthreads();

        const int q   = lane >> 4;
        const int r15 = lane & 15;
#pragma unroll
        for (int kk = 0; kk < 64; kk += 32) {
            int j = (kk >> 3) + q;
            f16x8 a[4], b[4];
#pragma unroll
            for (int mt = 0; mt < 4; ++mt) {
                int row = wm * 64 + mt * 16 + r15;
                a[mt] = *(const f16x8*)(smem + row * 128 + ((j ^ (row & 7)) * 16));
            }
#pragma unroll
            for (int nt = 0; nt < 4; ++nt) {
                int row = wn * 64 + nt * 16 + r15;
                b[nt] = *(const f16x8*)(smem + 16384 + row * 128 + ((j ^ (row & 7)) * 16));
            }
#pragma unroll
            for (int mt = 0; mt < 4; ++mt)
#pragma unroll
                for (int nt = 0; nt < 4; ++nt)
                    acc[mt][nt] = __builtin_amdgcn_mfma_f32_16x16x32_f16(a[mt], b[nt],
                                                                         acc[mt][nt], 0, 0, 0);
        }
        __syncthreads();
    }

    const int q   = lane >> 4;
    const int r15 = lane & 15;
#pragma unroll
    for (int mt = 0; mt < 4; ++mt)
#pragma unroll
        for (int nt = 0; nt < 4; ++nt) {
            int o     = bn * 128 + wn * 64 + nt * 16 + r15;
            int tbase = bm * 128 + wm * 64 + mt * 16 + q * 4;
#pragma unroll
            for (int r = 0; r < 4; ++r)
                out[(size_t)(tbase + r) * OUT_F + o] = acc[mt][nt][r];
        }
}

__global__ __launch_bounds__(256) void gemm_kernel(const float* __restrict__ X,
                                                   const _Float16* __restrict__ W,
                                                   float* __restrict__ out) {
    __shared__ __align__(16) _Float16 As[128 * 72];
    __shared__ __align__(16) _Float16 Bs[128 * 72];
    const int tid  = threadIdx.x;
    const int lane = tid & 63;
    const int w    = tid >> 6;
    const int wm   = w >> 1;
    const int wn   = w & 1;
    const int bm   = blockIdx.y;
    const int bn   = blockIdx.x;
    const int srow = tid >> 3;
    const int sch  = tid & 7;

    const float*    Xb = X + (size_t)(bm * 128) * IN_F;
    const _Float16* Wb = W + (size_t)(bn * 128) * IN_F;

    floatx4 acc[4][4] = {};

    for (int k0 = 0; k0 < IN_F; k0 += 64) {
#pragma unroll
        for (int p = 0; p < 4; ++p) {
            int row = p * 32 + srow;
            const float* gp = Xb + (size_t)row * IN_F + k0 + sch * 8;
            float4 u = ((const float4*)gp)[0];
            float4 v = ((const float4*)gp)[1];
            f16x8 h;
            h[0] = (_Float16)u.x; h[1] = (_Float16)u.y;
            h[2] = (_Float16)u.z; h[3] = (_Float16)u.w;
            h[4] = (_Float16)v.x; h[5] = (_Float16)v.y;
            h[6] = (_Float16)v.z; h[7] = (_Float16)v.w;
            *(f16x8*)&As[row * 72 + sch * 8] = h;
        }
#pragma unroll
        for (int p = 0; p < 4; ++p) {
            int row = p * 32 + srow;
            *(f16x8*)&Bs[row * 72 + sch * 8] =
                *(const f16x8*)(Wb + (size_t)row * IN_F + k0 + sch * 8);
        }
        __syncthreads();

        const int q   = lane >> 4;
        const int r15 = lane & 15;
#pragma unroll
        for (int kk = 0; kk < 64; kk += 32) {
            int j = (kk >> 3) + q;
            f16x8 a[4], b[4];
#pragma unroll
            for (int mt = 0; mt < 4; ++mt) {
                int row = wm * 64 + mt * 16 + r15;
                a[mt] = *(const f16x8*)&As[row * 72 + j * 8];
            }
#pragma unroll
            for (int nt = 0; nt < 4; ++nt) {
                int row = wn * 64 + nt * 16 + r15;
                b[nt] = *(const f16x8*)&Bs[row * 72 + j * 8];
            }
#pragma unroll
            for (int mt = 0; mt < 4; ++mt)
#pragma unroll
                for (int nt = 0; nt < 4; ++nt)
                    acc[mt][nt] = __builtin_amdgcn_mfma_f32_16x16x32_f16(a[mt], b[nt],
                                                                         acc[mt][nt], 0, 0, 0);
        }
        __syncthreads();
    }

    const int q   = lane >> 4;
    const int r15 = lane & 15;
#pragma unroll
    for (int mt = 0; mt < 4; ++mt)
#pragma unroll
        for (int nt = 0; nt < 4; ++nt) {
            int o     = bn * 128 + wn * 64 + nt * 16 + r15;
            int tbase = bm * 128 + wm * 64 + mt * 16 + q * 4;
#pragma unroll
            for (int r = 0; r < 4; ++r)
                out[(size_t)(tbase + r) * OUT_F + o] = acc[mt][nt][r];
        }
}

// ---------------- launch ----------------

extern "C" void kernel_launch(void* const* d_in, const int* in_sizes, int n_in,
                              void* d_out, int out_size, void* d_ws, size_t ws_size,
                              hipStream_t stream) {
    const float* x      = (const float*)d_in[0];
    const int*   bp     = (const int*)d_in[1];
    const float* scales = (const float*)d_in[2];
    const void*  vals   = (const void*)d_in[3];
    const int*   cols   = (const int*)d_in[4];
    float*       out    = (float*)d_out;

    _Float16* wh = (_Float16*)d_ws;                                    // 33.5 MB
    const size_t wh_bytes = (size_t)OUT_F * IN_F * 2;
    const size_t xh_bytes = (size_t)TOK * IN_F * 2;                    // 67 MB

    static int use256 = -1;
    if (use256 < 0) {
        hipError_t e = hipFuncSetAttribute((const void*)gemm256_kernel,
                                           hipFuncAttributeMaxDynamicSharedMemorySize,
                                           131072);
        use256 = (e == hipSuccess) ? 1 : 0;
    }

    dequant_w_kernel<<<OUT_F * IN_F / 8 / 256, 256, 0, stream>>>(bp, scales, wh);
    sparse_add_kernel<<<(NNZ + 255) / 256, 256, 0, stream>>>(vals, cols, wh);

    if (ws_size >= wh_bytes + xh_bytes) {
        _Float16* xh = (_Float16*)((char*)d_ws + wh_bytes);
        cvt_x_kernel<<<TOK * IN_F / 8 / 256, 256, 0, stream>>>(x, xh);
        if (use256) {
            gemm256_kernel<<<dim3(512), 512, 131072, stream>>>(xh, wh, out);
        } else {
            dim3 grid(OUT_F / 128, TOK / 128);
            gemm_fast_kernel<<<grid, 256, 0, stream>>>(xh, wh, out);
        }
    } else {
        dim3 grid(OUT_F / 128, TOK / 128);
        gemm_kernel<<<grid, 256, 0, stream>>>(x, wh, out);
    }
}

// Round 3
// 506.829 us; speedup vs baseline: 1.1932x; 1.0338x over previous
//
#include <hip/hip_runtime.h>
#include <hip/hip_fp16.h>

#define IN_F 4096
#define OUT_F 4096
#define TOK 8192
#define NNZ_PER_ROW 205
#define NNZ (OUT_F * NNZ_PER_ROW)

typedef __attribute__((ext_vector_type(8))) _Float16 f16x8;
typedef __attribute__((ext_vector_type(4))) float floatx4;

// ---------------- prep kernels (unchanged, known-good) ----------------

__global__ __launch_bounds__(256) void cvt_x_kernel(const float* __restrict__ x,
                                                    _Float16* __restrict__ xh) {
    int t = blockIdx.x * 256 + threadIdx.x;      // one thread = 8 elements
    const float4* p = (const float4*)x + (size_t)t * 2;
    float4 a = p[0], b = p[1];
    f16x8 h;
    h[0] = (_Float16)a.x; h[1] = (_Float16)a.y; h[2] = (_Float16)a.z; h[3] = (_Float16)a.w;
    h[4] = (_Float16)b.x; h[5] = (_Float16)b.y; h[6] = (_Float16)b.z; h[7] = (_Float16)b.w;
    ((f16x8*)xh)[t] = h;
}

__global__ __launch_bounds__(256) void dequant_w_kernel(const int* __restrict__ bp,
                                                        const float* __restrict__ scales,
                                                        _Float16* __restrict__ wh) {
    int t = blockIdx.x * 256 + threadIdx.x;      // one thread = 8 elements
    int row = t >> 9;                            // 512 threads per 4096-wide row
    float s = scales[row];
    const int4* p = (const int4*)bp + (size_t)t * 2;
    int4 a = p[0], b = p[1];
    f16x8 h;
    h[0] = (_Float16)((float)(a.x - 128) * s);
    h[1] = (_Float16)((float)(a.y - 128) * s);
    h[2] = (_Float16)((float)(a.z - 128) * s);
    h[3] = (_Float16)((float)(a.w - 128) * s);
    h[4] = (_Float16)((float)(b.x - 128) * s);
    h[5] = (_Float16)((float)(b.y - 128) * s);
    h[6] = (_Float16)((float)(b.z - 128) * s);
    h[7] = (_Float16)((float)(b.w - 128) * s);
    ((f16x8*)wh)[t] = h;
}

__global__ __launch_bounds__(256) void sparse_add_kernel(const void* __restrict__ vals_raw,
                                                         const int* __restrict__ cols,
                                                         _Float16* __restrict__ wh) {
    int k = blockIdx.x * 256 + threadIdx.x;
    if (k >= NNZ) return;

    const float*    vf = (const float*)vals_raw;
    const _Float16* vh = (const _Float16*)vals_raw;
    float mx = 0.f;
    for (int i = 0; i < 64; ++i) {
        float a = __builtin_fabsf(vf[i]);
        mx = a > mx ? a : mx;
    }
    const bool is_f32 = (mx > 1e-6f) && (mx < 1.0f);

    int row  = k / NNZ_PER_ROW;
    int rbeg = row * NNZ_PER_ROW;
    int rend = rbeg + NNZ_PER_ROW;
    int c    = cols[k];
    if (k != rbeg && cols[k - 1] == c) return;   // not first of its run

    float s = is_f32 ? vf[k] : (float)vh[k];
    for (int k2 = k + 1; k2 < rend && cols[k2] == c; ++k2)
        s += is_f32 ? vf[k2] : (float)vh[k2];

    _Float16* p = wh + (size_t)row * IN_F + c;
    *p = (_Float16)((float)*p + s);
}

// ---------------- GEMM: 256x256 tile, fragment-double-buffered schedule ----
// out[T][O] = Xh[T][K] * Wh[O][K]^T.  BM=BN=256, BK=64, 512 thr = 8 waves
// (2M x 4N), per-wave C = 128x64 -> acc[8][4] x floatx4.
//
// LDS (dynamic, 128 KiB), per 64KB buffer b: A @ +0, B @ +32768, each
// 256 rows x 128B.  Zero-conflict layout (measured r2): slot s of row r
// holds global 16B K-chunk s ^ (r&7); staging permutes the GLOBAL source
// (e = (lane&7)^(lane>>3)), LDS dest linear; reads use slot0 ^ (KKH*64).
//
// Fragment double-buffering: phase p issues the ds_reads for phase p+1's
// fragments, then MFMAs phase p's fragments.  The compiler's counted
// lgkmcnt before the MFMA cluster waits only for the PREVIOUS phase's
// reads, so the just-issued reads complete under the MFMA window (no
// exposed read window; mid-phase barrier eliminated -> 4 barriers/tile).
//   ph0: read A(mq1,kk0)->sa1;            stage A1(kt+1)->ob; MFMA(sa0,sb0,mq0)
//   ph1: read A(mq0,kk1)->sa0, B(kk1)->sb1; stage A2(kt+1)->ob; MFMA(sa1,sb0,mq1)
//   ph2: read A(mq1,kk1)->sa1;                                MFMA(sa0,sb1,mq0)
//        vmcnt(0)   <- per-wave drain BEFORE barrier publishes all stages
//   ph3: read next-tile A(mq0,kk0)->sa0, B(kk0)->sb0 from ob;
//        stage B1,B2(kt+2)->buf;                              MFMA(sa1,sb1,mq1)
// Stage/read hazards: A stages write the other buffer (last read >=2
// barriers prior); B(kt+2) stage writes buf B whose fragments were last
// read ph1, completed before ph2's MFMA-wait, one barrier before the
// stage.  ph3's prefetch from ob is safe: every wave did vmcnt(0) before
// the ph2 barrier, so all stages into ob (issued >=1 phase = >=1200 cyc
// earlier) have landed.

__global__ __launch_bounds__(512, 2) void gemm256_kernel(const _Float16* __restrict__ X,
                                                         const _Float16* __restrict__ W,
                                                         float* __restrict__ out) {
    extern __shared__ char smem[];               // 131072 bytes
    const int tid  = threadIdx.x;
    const int lane = tid & 63;
    const int w    = tid >> 6;                   // 0..7
    const int wm   = w >> 2;                     // 0..1  (M)
    const int wn   = w & 3;                      // 0..3  (N)

    // bijective XCD swizzle: 512 blocks, 64 contiguous logical tiles per XCD
    const int bid = blockIdx.x;
    const int swz = (bid & 7) * 64 + (bid >> 3);
    const int bm  = swz >> 4;                    // 0..31
    const int bn  = swz & 15;                    // 0..15

    const _Float16* Ap = X + (size_t)(bm * 256) * IN_F;
    const _Float16* Bp = W + (size_t)(bn * 256) * IN_F;

    // staging lane geometry: chunk = 8 rows x 128B = 1024B; within a chunk
    // lane>>3 = row, lane&7 = LDS slot; global chunk fetched = slot ^ row&7.
    const int l8 = lane >> 3;
    const int e  = (lane & 7) ^ l8;              // per-lane constant

    auto stage = [&](const _Float16* panel, int ldsBase, int rowBase, int kcol) {
#pragma unroll
        for (int j = 0; j < 2; ++j) {
            int ch = w * 2 + j;
            const _Float16* gp = panel + (size_t)(rowBase + ch * 8 + l8) * IN_F + kcol + e * 8;
            char* lp = smem + ldsBase + ch * 1024;   // wave-uniform base
            __builtin_amdgcn_global_load_lds(
                (const __attribute__((address_space(1))) void*)gp,
                (__attribute__((address_space(3))) void*)lp, 16, 0, 0);
        }
    };

    const int q     = lane >> 4;
    const int r15   = lane & 15;
    const int slot0 = (q ^ (r15 & 7)) * 16;      // kk0 slot byte; kk1 = slot0^64

    floatx4 acc[8][4] = {};
    f16x8 sa0[4], sa1[4], sb0[4], sb1[4];

#define DS_A(DST, MQ, KKH, BUFOFF) do {                                         \
    const char* Ab_ = smem + (BUFOFF);                                          \
    _Pragma("unroll")                                                           \
    for (int mt = 0; mt < 4; ++mt)                                              \
        DST[mt] = *(const f16x8*)(Ab_ + (wm * 128 + (MQ) * 64 + mt * 16 + r15) * 128 \
                                      + (slot0 ^ ((KKH) * 64)));                \
} while (0)

#define DS_B(DST, KKH, BUFOFF) do {                                             \
    const char* Bb_ = smem + (BUFOFF) + 32768;                                  \
    _Pragma("unroll")                                                           \
    for (int nt = 0; nt < 4; ++nt)                                              \
        DST[nt] = *(const f16x8*)(Bb_ + (wn * 64 + nt * 16 + r15) * 128         \
                                      + (slot0 ^ ((KKH) * 64)));                \
} while (0)

#define MFMA4(SA, SB, MQ) do {                                                  \
    __builtin_amdgcn_s_setprio(1);                                              \
    _Pragma("unroll")                                                           \
    for (int mt = 0; mt < 4; ++mt)                                              \
        _Pragma("unroll")                                                       \
        for (int nt = 0; nt < 4; ++nt)                                          \
            acc[(MQ) * 4 + mt][nt] = __builtin_amdgcn_mfma_f32_16x16x32_f16(    \
                SA[mt], SB[nt], acc[(MQ) * 4 + mt][nt], 0, 0, 0);               \
    __builtin_amdgcn_s_setprio(0);                                              \
} while (0)

    // prologue: tile 0 fully + B(1); drain; preload ph0 fragment set
    stage(Bp, 32768, 0, 0);            // B1(0)
    stage(Bp, 49152, 128, 0);          // B2(0)
    stage(Ap, 0, 0, 0);                // A1(0)
    stage(Ap, 16384, 128, 0);          // A2(0)
    stage(Bp, 65536 + 32768, 0, 64);   // B1(1)
    stage(Bp, 65536 + 49152, 128, 64); // B2(1)
    asm volatile("s_waitcnt vmcnt(0)" ::: "memory");
    __builtin_amdgcn_s_barrier();
    DS_A(sa0, 0, 0, 0);
    DS_B(sb0, 0, 0);

    for (int kt = 0; kt < 64; ++kt) {
        const int buf = (kt & 1) << 16;
        const int ob  = buf ^ 65536;             // other buffer

        // ---- phase 0: MFMA(mq0,kk0); prefetch A(mq1,kk0); stage A1(kt+1)
        DS_A(sa1, 1, 0, buf);
        if (kt < 63) stage(Ap, ob, 0, (kt + 1) * 64);
        __builtin_amdgcn_sched_barrier(0);
        MFMA4(sa0, sb0, 0);
        __builtin_amdgcn_s_barrier();

        // ---- phase 1: MFMA(mq1,kk0); prefetch A(mq0,kk1)+B(kk1); stage A2(kt+1)
        DS_A(sa0, 0, 1, buf);
        DS_B(sb1, 1, buf);
        if (kt < 63) stage(Ap, ob + 16384, 128, (kt + 1) * 64);
        __builtin_amdgcn_sched_barrier(0);
        MFMA4(sa1, sb0, 1);
        __builtin_amdgcn_s_barrier();

        // ---- phase 2: MFMA(mq0,kk1); prefetch A(mq1,kk1); vmcnt(0) pre-barrier
        DS_A(sa1, 1, 1, buf);
        __builtin_amdgcn_sched_barrier(0);
        MFMA4(sa0, sb1, 0);
        asm volatile("s_waitcnt vmcnt(0)" ::: "memory");
        __builtin_amdgcn_s_barrier();

        // ---- phase 3: MFMA(mq1,kk1); prefetch next tile's (mq0,kk0) set; stage B(kt+2)
        if (kt < 63) {
            DS_A(sa0, 0, 0, ob);
            DS_B(sb0, 0, ob);
        }
        if (kt < 62) {
            stage(Bp, buf + 32768, 0, (kt + 2) * 64);
            stage(Bp, buf + 49152, 128, (kt + 2) * 64);
        }
        __builtin_amdgcn_sched_barrier(0);
        MFMA4(sa1, sb1, 1);
        __builtin_amdgcn_s_barrier();
    }

#undef DS_A
#undef DS_B
#undef MFMA4

#pragma unroll
    for (int mq = 0; mq < 2; ++mq)
#pragma unroll
        for (int mt = 0; mt < 4; ++mt)
#pragma unroll
            for (int nt = 0; nt < 4; ++nt) {
                const int o    = bn * 256 + wn * 64 + nt * 16 + r15;
                const int trow = bm * 256 + wm * 128 + mq * 64 + mt * 16 + q * 4;
                const floatx4 v = acc[mq * 4 + mt][nt];
#pragma unroll
                for (int r = 0; r < 4; ++r)
                    out[(size_t)(trow + r) * OUT_F + o] = v[r];
            }
}

// ---------------- GEMM fallbacks (previous known-good kernels) -------------

__global__ __launch_bounds__(256) void gemm_fast_kernel(const _Float16* __restrict__ X,
                                                        const _Float16* __restrict__ W,
                                                        float* __restrict__ out) {
    __shared__ __align__(1024) char smem[32768];   // A: [0,16K)  B: [16K,32K)
    const int tid  = threadIdx.x;
    const int lane = tid & 63;
    const int w    = tid >> 6;
    const int wm   = w >> 1;
    const int wn   = w & 1;
    const int bm   = blockIdx.y;
    const int bn   = blockIdx.x;

    const int l8 = lane >> 3;
    const int ls = lane & 7;
    const int e  = ls ^ l8;

    floatx4 acc[4][4] = {};

    for (int k0 = 0; k0 < IN_F; k0 += 64) {
#pragma unroll
        for (int j = 0; j < 4; ++j) {
            int c   = w * 4 + j;
            int row = c * 8 + l8;
            const _Float16* gp = X + ((size_t)(bm * 128 + row)) * IN_F + k0 + e * 8;
            char* lp = smem + c * 1024;
            __builtin_amdgcn_global_load_lds((const __attribute__((address_space(1))) void*)gp,
                                             (__attribute__((address_space(3))) void*)lp,
                                             16, 0, 0);
        }
#pragma unroll
        for (int j = 0; j < 4; ++j) {
            int c   = w * 4 + j;
            int row = c * 8 + l8;
            const _Float16* gp = W + ((size_t)(bn * 128 + row)) * IN_F + k0 + e * 8;
            char* lp = smem + 16384 + c * 1024;
            __builtin_amdgcn_global_load_lds((const __attribute__((address_space(1))) void*)gp,
                                             (__attribute__((address_space(3))) void*)lp,
                                             16, 0, 0);
        }
        __syncthreads();

        const int q   = lane >> 4;
        const int r15 = lane & 15;
#pragma unroll
        for (int kk = 0; kk < 64; kk += 32) {
            int j = (kk >> 3) + q;
            f16x8 a[4], b[4];
#pragma unroll
            for (int mt = 0; mt < 4; ++mt) {
                int row = wm * 64 + mt * 16 + r15;
                a[mt] = *(const f16x8*)(smem + row * 128 + ((j ^ (row & 7)) * 16));
            }
#pragma unroll
            for (int nt = 0; nt < 4; ++nt) {
                int row = wn * 64 + nt * 16 + r15;
                b[nt] = *(const f16x8*)(smem + 16384 + row * 128 + ((j ^ (row & 7)) * 16));
            }
#pragma unroll
            for (int mt = 0; mt < 4; ++mt)
#pragma unroll
                for (int nt = 0; nt < 4; ++nt)
                    acc[mt][nt] = __builtin_amdgcn_mfma_f32_16x16x32_f16(a[mt], b[nt],
                                                                         acc[mt][nt], 0, 0, 0);
        }
        __syncthreads();
    }

    const int q   = lane >> 4;
    const int r15 = lane & 15;
#pragma unroll
    for (int mt = 0; mt < 4; ++mt)
#pragma unroll
        for (int nt = 0; nt < 4; ++nt) {
            int o     = bn * 128 + wn * 64 + nt * 16 + r15;
            int tbase = bm * 128 + wm * 64 + mt * 16 + q * 4;
#pragma unroll
            for (int r = 0; r < 4; ++r)
                out[(size_t)(tbase + r) * OUT_F + o] = acc[mt][nt][r];
        }
}

__global__ __launch_bounds__(256) void gemm_kernel(const float* __restrict__ X,
                                                   const _Float16* __restrict__ W,
                                                   float* __restrict__ out) {
    __shared__ __align__(16) _Float16 As[128 * 72];
    __shared__ __align__(16) _Float16 Bs[128 * 72];
    const int tid  = threadIdx.x;
    const int lane = tid & 63;
    const int w    = tid >> 6;
    const int wm   = w >> 1;
    const int wn   = w & 1;
    const int bm   = blockIdx.y;
    const int bn   = blockIdx.x;
    const int srow = tid >> 3;
    const int sch  = tid & 7;

    const float*    Xb = X + (size_t)(bm * 128) * IN_F;
    const _Float16* Wb = W + (size_t)(bn * 128) * IN_F;

    floatx4 acc[4][4] = {};

    for (int k0 = 0; k0 < IN_F; k0 += 64) {
#pragma unroll
        for (int p = 0; p < 4; ++p) {
            int row = p * 32 + srow;
            const float* gp = Xb + (size_t)row * IN_F + k0 + sch * 8;
            float4 u = ((const float4*)gp)[0];
            float4 v = ((const float4*)gp)[1];
            f16x8 h;
            h[0] = (_Float16)u.x; h[1] = (_Float16)u.y;
            h[2] = (_Float16)u.z; h[3] = (_Float16)u.w;
            h[4] = (_Float16)v.x; h[5] = (_Float16)v.y;
            h[6] = (_Float16)v.z; h[7] = (_Float16)v.w;
            *(f16x8*)&As[row * 72 + sch * 8] = h;
        }
#pragma unroll
        for (int p = 0; p < 4; ++p) {
            int row = p * 32 + srow;
            *(f16x8*)&Bs[row * 72 + sch * 8] =
                *(const f16x8*)(Wb + (size_t)row * IN_F + k0 + sch * 8);
        }
        __syncthreads();

        const int q   = lane >> 4;
        const int r15 = lane & 15;
#pragma unroll
        for (int kk = 0; kk < 64; kk += 32) {
            int j = (kk >> 3) + q;
            f16x8 a[4], b[4];
#pragma unroll
            for (int mt = 0; mt < 4; ++mt) {
                int row = wm * 64 + mt * 16 + r15;
                a[mt] = *(const f16x8*)&As[row * 72 + j * 8];
            }
#pragma unroll
            for (int nt = 0; nt < 4; ++nt) {
                int row = wn * 64 + nt * 16 + r15;
                b[nt] = *(const f16x8*)&Bs[row * 72 + j * 8];
            }
#pragma unroll
            for (int mt = 0; mt < 4; ++mt)
#pragma unroll
                for (int nt = 0; nt < 4; ++nt)
                    acc[mt][nt] = __builtin_amdgcn_mfma_f32_16x16x32_f16(a[mt], b[nt],
                                                                         acc[mt][nt], 0, 0, 0);
        }
        __syncthreads();
    }

    const int q   = lane >> 4;
    const int r15 = lane & 15;
#pragma unroll
    for (int mt = 0; mt < 4; ++mt)
#pragma unroll
        for (int nt = 0; nt < 4; ++nt) {
            int o     = bn * 128 + wn * 64 + nt * 16 + r15;
            int tbase = bm * 128 + wm * 64 + mt * 16 + q * 4;
#pragma unroll
            for (int r = 0; r < 4; ++r)
                out[(size_t)(tbase + r) * OUT_F + o] = acc[mt][nt][r];
        }
}

// ---------------- launch ----------------

extern "C" void kernel_launch(void* const* d_in, const int* in_sizes, int n_in,
                              void* d_out, int out_size, void* d_ws, size_t ws_size,
                              hipStream_t stream) {
    const float* x      = (const float*)d_in[0];
    const int*   bp     = (const int*)d_in[1];
    const float* scales = (const float*)d_in[2];
    const void*  vals   = (const void*)d_in[3];
    const int*   cols   = (const int*)d_in[4];
    float*       out    = (float*)d_out;

    _Float16* wh = (_Float16*)d_ws;                                    // 33.5 MB
    const size_t wh_bytes = (size_t)OUT_F * IN_F * 2;
    const size_t xh_bytes = (size_t)TOK * IN_F * 2;                    // 67 MB

    static int use256 = -1;
    if (use256 < 0) {
        hipError_t e = hipFuncSetAttribute((const void*)gemm256_kernel,
                                           hipFuncAttributeMaxDynamicSharedMemorySize,
                                           131072);
        use256 = (e == hipSuccess) ? 1 : 0;
    }

    dequant_w_kernel<<<OUT_F * IN_F / 8 / 256, 256, 0, stream>>>(bp, scales, wh);
    sparse_add_kernel<<<(NNZ + 255) / 256, 256, 0, stream>>>(vals, cols, wh);

    if (ws_size >= wh_bytes + xh_bytes) {
        _Float16* xh = (_Float16*)((char*)d_ws + wh_bytes);
        cvt_x_kernel<<<TOK * IN_F / 8 / 256, 256, 0, stream>>>(x, xh);
        if (use256) {
            gemm256_kernel<<<dim3(512), 512, 131072, stream>>>(xh, wh, out);
        } else {
            dim3 grid(OUT_F / 128, TOK / 128);
            gemm_fast_kernel<<<grid, 256, 0, stream>>>(xh, wh, out);
        }
    } else {
        dim3 grid(OUT_F / 128, TOK / 128);
        gemm_kernel<<<grid, 256, 0, stream>>>(x, wh, out);
    }
}